// Round 7
// baseline (1790.291 us; speedup 1.0000x reference)
//
#include <hip/hip_runtime.h>
#include <stdint.h>
#include <math.h>

// Problem constants (all fp32 per reference)
#define TT 256
#define BB 256
#define II 9
#define HH 1024
#define AAx 4
#define RR 38
#define BH (BB*HH)
#define NJB 16          // col-blocks per row-group (64 cols each)

typedef __attribute__((ext_vector_type(8))) short short8;
typedef __attribute__((ext_vector_type(4))) float f32x4;
typedef __attribute__((ext_vector_type(4))) unsigned int u32x4;
typedef __attribute__((ext_vector_type(2))) unsigned int u32x2;

__device__ __forceinline__ float bf2f(unsigned short u){
  union{unsigned int i; float f;} v; v.i = ((unsigned int)u)<<16; return v.f;
}
__device__ __forceinline__ unsigned short f2bf(float f){
  union{float f; unsigned int i;} v; v.f = f;
  unsigned int r = (v.i + 0x7FFFu + ((v.i>>16)&1u)) >> 16;
  return (unsigned short)r;
}

// Coherent (cross-XCD) 16B load pair: bypass L1+L2 (sc0 sc1), served from
// MALL. Per-access coherence — the only protocol proven on this hardware.
#define ISSUE2(d0,d1,s0,s1)                                                   \
  asm volatile("global_load_dwordx4 %0, %2, off offset:" s0 " sc0 sc1\n\t"    \
               "global_load_dwordx4 %1, %2, off offset:" s1 " sc0 sc1"        \
               : "=&v"(d0), "=&v"(d1) : "v"(ap) : "memory")

// Counted wait that DEFINES the regs it makes ready ("+v" ties) so dependent
// split/MFMA cannot be hoisted above it (rule #18 hazard).
#define WAITP(n,q0,q1)                                                        \
  asm volatile("s_waitcnt vmcnt(" n ")" : "+v"(q0), "+v"(q1) :: "memory")

// Coherent write-through store.
#define STORE_CC(p,x)                                                         \
  asm volatile("global_store_dword %0, %1, off sc0 sc1" :: "v"(p), "v"(x) : "memory")

// RNE f32 pair -> packed 2xbf16 (no builtin on gfx950)
#define CVTPK(d,s0,s1)                                                        \
  asm("v_cvt_pk_bf16_f32 %0, %1, %2" : "=v"(d) : "v"(s0), "v"(s1))

// Persistent fp32 RNN.
// Grid: 256 blocks = 16 row-groups (g=bid&15, 16 batch rows) x 16 col-blocks
// (jb=bid>>4, 64 cols). 512 threads = 8 waves; wave w owns K-slice
// [128w,128w+128) of h2h (hi/lo split-bf16 B-fragments, 128 VGPRs).
// 3-term MFMA => ~2^-17 rel GEMM error.
// v2 (1372us): sc0|sc1 per-access coherence. v7 (1259us): cvt_pk split.
// v8: DATAFLOW FLAGS replace the full-group counter barrier. Wave w's input
//     slice comes from exactly blocks (g,2w),(g,2w+1); each block publishes
//     flag[g][jb]=t+1 (sc1, after all 4 epilogue waves drained — LDS ds_add
//     completion count, no extra barrier) and each wave waits only on its two
//     producers. Flag-pair load PRE-ISSUED before the partials barrier and
//     checked after the epilogue => loads for t+1 issue during other blocks'
//     epilogues; blocks skew instead of convoying. Raw s_barrier + explicit
//     lgkmcnt (no vmcnt drain at barriers); exact vmcnt ledger, all loop VMEM
//     in asm (9 outstanding: xv + 8 quads; waits 8/6/4/2/0). Ext B-fragments
//     moved to LDS (-32 VGPR). Bounded spins (clean fail, never hang).
__global__ __launch_bounds__(512, 2) void rnn_persist(
    const float* __restrict__ inp,  const float* __restrict__ hid0,
    const float* __restrict__ act,  const float* __restrict__ rew,
    const float* __restrict__ i2h,  const float* __restrict__ h2h,
    const float* __restrict__ a2h,  const float* __restrict__ r2h,
    const float* __restrict__ bh,   const float* __restrict__ rr,
    const int*   __restrict__ kact_p,
    float* __restrict__ out, int* __restrict__ cnt)
{
  __shared__ f32x4 part[8*4*64];            // 32 KB K-split partials
  __shared__ unsigned short sexth[16*32];   // 1 KB ext-A hi (inp|act|0)
  __shared__ unsigned short sextl[16*32];   // 1 KB ext-A lo
  __shared__ short8 sweh[4*64];             // 4 KB ext-B hi (wave0 fragments)
  __shared__ short8 swel[4*64];             // 4 KB ext-B lo
  __shared__ int done4[2];                  // epilogue completion (t parity)

  const int tid   = threadIdx.x;
  const int w     = tid >> 6;
  const int l     = tid & 63;
  const int row16 = l & 15;
  const int quad  = l >> 4;
  const int g     = blockIdx.x & 15;   // row-group (16 rows)
  const int jb    = blockIdx.x >> 4;   // col-block (64 cols)

  const float kact = (float)kact_p[0];

  // ---- register-stationary hi/lo B-fragments of h2h ----
  short8 wbh[4][4], wbl[4][4];
  #pragma unroll
  for (int ki=0; ki<4; ki++){
    const int kb = w*128 + ki*32 + quad*8;
    #pragma unroll
    for (int nt=0; nt<4; nt++){
      const int n = jb*64 + nt*16 + row16;
      short8 vh, vl;
      #pragma unroll
      for (int j=0; j<8; j++){
        const float bv = h2h[(size_t)(kb+j)*HH + n];
        const unsigned short hh = f2bf(bv);
        vh[j] = (short)hh;
        vl[j] = (short)f2bf(bv - bf2f(hh));
      }
      wbh[ki][nt] = vh; wbl[ki][nt] = vl;
    }
  }
  // ext B-fragments (wave 0 lanes): k<9 = i2h, 9..12 = kact*a2h, rest 0.
  // Stored to LDS (read back each step) to save 32 VGPRs.
  if (w == 0){
    #pragma unroll
    for (int nt=0; nt<4; nt++){
      short8 vh, vl;
      #pragma unroll
      for (int j=0; j<8; j++){
        const int k = quad*8 + j;
        const int n = jb*64 + nt*16 + row16;
        float bv = 0.f;
        if (k < II)          bv = i2h[(size_t)k*HH + n];
        else if (k < II+AAx) bv = kact * a2h[(size_t)(k-II)*HH + n];
        const unsigned short hh = f2bf(bv);
        vh[j] = (short)hh;
        vl[j] = (short)f2bf(bv - bf2f(hh));
      }
      sweh[nt*64 + l] = vh; swel[nt*64 + l] = vl;
    }
  }

  // ---- epilogue constants (waves 0..3 own cols; w>=4 would be OOB) ----
  const int ecol = jb*64 + w*16 + row16;
  float r_own = 0.f, romr = 0.f;
  float h_own[4] = {0,0,0,0}, rb[4] = {0,0,0,0};
  if (w < 4){
    r_own = rr[ecol];
    romr  = 1.f - r_own;
    #pragma unroll
    for (int i=0; i<4; i++){
      const int br = 16*g + 4*quad + i;
      h_own[i] = hid0[(size_t)br*HH + ecol];
      float s = bh[ecol];
      for (int q=0; q<RR; q++) s += rew[(size_t)br*RR + q] * r2h[(size_t)q*HH + ecol];
      rb[i] = s;
    }
  }

  // sext zero-init (k in [13,32) stays 0) + staging index precompute
  sexth[tid] = 0; sextl[tid] = 0;
  if (tid < 2) done4[tid] = 0;
  const int st_act = (tid < 16*13);
  const int st_row = st_act ? (tid / 13) : 0;
  const int st_q   = st_act ? (tid % 13) : 0;
  __syncthreads();    // prologue only; drains everything, ledger := 0

  const int arow = 16*g + row16;
  // flags region: d_ws+1024, 64 B per group, u32 per col-block
  unsigned* flown = (unsigned*)((char*)cnt + 1024 + (size_t)g*64 + (size_t)jb*4);
  const unsigned* fp = (const unsigned*)((char*)cnt + 1024 + (size_t)g*64 + (size_t)w*8);

  // ---- prologue issue: xv(t=0) then 8 state quads from hid0 (ledger = 9)
  float xvr;
  f32x4 L0a,L0b,L1a,L1b,L2a,L2b,L3a,L3b;
  u32x2 fpre;
  {
    const int br = 16*g + st_row;
    const float* xp0 = st_act
      ? ((st_q < II) ? inp + (size_t)br*II + st_q
                     : act + (size_t)br*AAx + (st_q - II))
      : inp;
    asm volatile("global_load_dword %0, %1, off" : "=&v"(xvr) : "v"(xp0) : "memory");
    const float* ap = hid0 + (size_t)arow*HH + (size_t)w*128 + quad*8;
    ISSUE2(L0a,L0b,"0","16");
    ISSUE2(L1a,L1b,"128","144");
    ISSUE2(L2a,L2b,"256","272");
    ISSUE2(L3a,L3b,"384","400");
  }

  for (int t=0; t<TT; t++){
    // --- stage this step's inp/act slice (hi/lo) into LDS ---
    asm volatile("s_waitcnt vmcnt(8)" : "+v"(xvr) :: "memory");   // xv ready
    if (st_act){
      const unsigned short hh = f2bf(xvr);
      sexth[st_row*32 + st_q] = hh;
      sextl[st_row*32 + st_q] = f2bf(xvr - bf2f(hh));
    }
    asm volatile("s_waitcnt lgkmcnt(0)" ::: "memory");
    __builtin_amdgcn_s_barrier();                                  // B1

    f32x4 acc[4];
    #pragma unroll
    for (int nt=0; nt<4; nt++){ acc[nt].x=0.f; acc[nt].y=0.f; acc[nt].z=0.f; acc[nt].w=0.f; }

    // one ki: cvt_pk hi/lo split (exact Sterbenz lo) + 12 MFMAs
    auto doKi = [&](int ki, const f32x4& q0, const f32x4& q1){
      u32x4 ahw, alw;
      CVTPK(ahw[0], q0[0], q0[1]);
      CVTPK(ahw[1], q0[2], q0[3]);
      CVTPK(ahw[2], q1[0], q1[1]);
      CVTPK(ahw[3], q1[2], q1[3]);
      const float l0 = q0[0] - __builtin_bit_cast(float, ahw[0] << 16);
      const float l1 = q0[1] - __builtin_bit_cast(float, ahw[0] & 0xFFFF0000u);
      const float l2 = q0[2] - __builtin_bit_cast(float, ahw[1] << 16);
      const float l3 = q0[3] - __builtin_bit_cast(float, ahw[1] & 0xFFFF0000u);
      const float l4 = q1[0] - __builtin_bit_cast(float, ahw[2] << 16);
      const float l5 = q1[1] - __builtin_bit_cast(float, ahw[2] & 0xFFFF0000u);
      const float l6 = q1[2] - __builtin_bit_cast(float, ahw[3] << 16);
      const float l7 = q1[3] - __builtin_bit_cast(float, ahw[3] & 0xFFFF0000u);
      CVTPK(alw[0], l0, l1);
      CVTPK(alw[1], l2, l3);
      CVTPK(alw[2], l4, l5);
      CVTPK(alw[3], l6, l7);
      const short8 ah = __builtin_bit_cast(short8, ahw);
      const short8 al = __builtin_bit_cast(short8, alw);
      #pragma unroll
      for (int nt=0; nt<4; nt++){
        acc[nt] = __builtin_amdgcn_mfma_f32_16x16x32_bf16(ah, wbh[ki][nt], acc[nt], 0,0,0);
        acc[nt] = __builtin_amdgcn_mfma_f32_16x16x32_bf16(al, wbh[ki][nt], acc[nt], 0,0,0);
        acc[nt] = __builtin_amdgcn_mfma_f32_16x16x32_bf16(ah, wbl[ki][nt], acc[nt], 0,0,0);
      }
    };

    WAITP("6",L0a,L0b); doKi(0,L0a,L0b);
    WAITP("4",L1a,L1b); doKi(1,L1a,L1b);
    WAITP("2",L2a,L2b); doKi(2,L2a,L2b);
    WAITP("0",L3a,L3b); doKi(3,L3a,L3b);

    // ext contribution (wave 0): inp@i2h + kact*(act@a2h)
    if (w == 0){
      const short8 aeh = *(const short8*)&sexth[row16*32 + quad*8];
      const short8 ael = *(const short8*)&sextl[row16*32 + quad*8];
      #pragma unroll
      for (int nt=0; nt<4; nt++){
        const short8 bh8 = sweh[nt*64 + l];
        const short8 bl8 = swel[nt*64 + l];
        acc[nt] = __builtin_amdgcn_mfma_f32_16x16x32_bf16(aeh, bh8, acc[nt], 0,0,0);
        acc[nt] = __builtin_amdgcn_mfma_f32_16x16x32_bf16(ael, bh8, acc[nt], 0,0,0);
        acc[nt] = __builtin_amdgcn_mfma_f32_16x16x32_bf16(aeh, bl8, acc[nt], 0,0,0);
      }
    }

    // K-split partials + PRE-ISSUE producer flag-pair load for t+1
    #pragma unroll
    for (int nt=0; nt<4; nt++) part[(w*4 + nt)*64 + l] = acc[nt];
    if (t+1 < TT){
      asm volatile("global_load_dwordx2 %0, %1, off sc0 sc1"
                   : "=&v"(fpre) : "v"(fp) : "memory");
    }
    asm volatile("s_waitcnt lgkmcnt(0)" ::: "memory");
    __builtin_amdgcn_s_barrier();                                  // B2

    if (w < 4){
      f32x4 z = part[(0*4 + w)*64 + l];
      #pragma unroll
      for (int s=1; s<8; s++){
        const f32x4 p = part[(s*4 + w)*64 + l];
        z.x += p.x; z.y += p.y; z.z += p.z; z.w += p.w;
      }
      const float zz[4] = {z.x, z.y, z.z, z.w};
      #pragma unroll
      for (int i=0; i<4; i++){
        const float x  = zz[i] + rb[i];
        const float hc = tanhf(x);
        const float hn = romr*hc + r_own*h_own[i];
        h_own[i] = hn;
        const int br = 16*g + 4*quad + i;
        float* op = out + (size_t)t*BH + (size_t)br*HH + ecol;
        STORE_CC(op, hn);
      }
      asm volatile("s_waitcnt vmcnt(0)" ::: "memory");   // stores (+fpre) acked
      if (l == 0){
        const int old = __hip_atomic_fetch_add(&done4[t&1], 1,
                          __ATOMIC_RELAXED, __HIP_MEMORY_SCOPE_WORKGROUP);
        if (old == 3){   // 4th (last) epilogue wave: all 64 cols at MALL
          const unsigned fvv = (unsigned)(t+1);
          asm volatile("global_store_dword %0, %1, off sc0 sc1"
                       :: "v"(flown), "v"(fvv) : "memory");
          asm volatile("s_waitcnt vmcnt(0)" ::: "memory");
          __hip_atomic_store(&done4[t&1], 0, __ATOMIC_RELAXED,
                             __HIP_MEMORY_SCOPE_WORKGROUP);
        }
      }
    }

    // dataflow wait on the 2 producers of wave w's slice, then issue t+1
    if (t+1 < TT){
      const unsigned tgt = (unsigned)(t+1);
      asm volatile("s_waitcnt vmcnt(0)" : "+v"(fpre) :: "memory");
      if (!(fpre[0] >= tgt && fpre[1] >= tgt)){
        if (l == 0){
          u32x2 fv;
          for (int it=0; it<(1<<16); ++it){
            asm volatile("global_load_dwordx2 %0, %1, off sc0 sc1\n\t"
                         "s_waitcnt vmcnt(0)"
                         : "=&v"(fv) : "v"(fp) : "memory");
            if (fv[0] >= tgt && fv[1] >= tgt) break;
            __builtin_amdgcn_s_sleep(1);
          }
        }
      }
      const int br = 16*g + st_row;
      const float* xpn = st_act
        ? ((st_q < II) ? inp + ((size_t)(t+1)*BB + br)*II  + st_q
                       : act + ((size_t)(t+1)*BB + br)*AAx + (st_q - II))
        : inp;
      asm volatile("global_load_dword %0, %1, off" : "=&v"(xvr) : "v"(xpn) : "memory");
      const float* ap = out + (size_t)t*BH + (size_t)arow*HH + (size_t)w*128 + quad*8;
      ISSUE2(L0a,L0b,"0","16");
      ISSUE2(L1a,L1b,"128","144");
      ISSUE2(L2a,L2b,"256","272");
      ISSUE2(L3a,L3b,"384","400");
    }
  }
}

extern "C" void kernel_launch(void* const* d_in, const int* in_sizes, int n_in,
                              void* d_out, int out_size, void* d_ws, size_t ws_size,
                              hipStream_t stream) {
  const float* inp  = (const float*)d_in[0];
  const float* hid0 = (const float*)d_in[1];
  const float* act  = (const float*)d_in[2];
  const float* rew  = (const float*)d_in[3];
  const float* i2h  = (const float*)d_in[4];
  const float* h2h  = (const float*)d_in[5];
  const float* a2h  = (const float*)d_in[6];
  const float* r2h  = (const float*)d_in[7];
  const float* bh   = (const float*)d_in[8];
  const float* rr   = (const float*)d_in[9];
  const int*   kact = (const int*)d_in[10];
  float* out = (float*)d_out;

  int* cnt = (int*)d_ws;   // 4 KB: [1024,2048) = dataflow flags (16 groups x 64 B)
  hipMemsetAsync(d_ws, 0, 4096, stream);

  rnn_persist<<<256, 512, 0, stream>>>(inp, hid0, act, rew, i2h, h2h, a2h, r2h,
                                       bh, rr, kact, out, cnt);
}